// Round 1
// baseline (1030.840 us; speedup 1.0000x reference)
//
#include <hip/hip_runtime.h>

typedef unsigned short u16;
typedef short s16x8 __attribute__((ext_vector_type(8)));
typedef __bf16 bf16x8 __attribute__((ext_vector_type(8)));
typedef float f32x4 __attribute__((ext_vector_type(4)));

// ---------- helpers ----------

__device__ __forceinline__ u16 f2bf(float f) {
  union { float f; unsigned u; } x; x.f = f;
  unsigned r = (x.u + 0x7fffu + ((x.u >> 16) & 1u)) >> 16;  // RNE
  return (u16)r;
}

__device__ __forceinline__ f32x4 mfma_bf16_16x16x32(s16x8 a, s16x8 b, f32x4 c) {
  return __builtin_amdgcn_mfma_f32_16x16x32_bf16(
      __builtin_bit_cast(bf16x8, a), __builtin_bit_cast(bf16x8, b), c, 0, 0, 0);
}

__device__ __forceinline__ void gl_lds16(const u16* g, u16* l) {
  __builtin_amdgcn_global_load_lds(
      (__attribute__((address_space(1))) unsigned int*)g,
      (__attribute__((address_space(3))) unsigned int*)l, 16, 0, 0);
}

// P-tile LDS swizzle: [64][64] u16 (128B row stride). XOR the 16B-slot index
// (col>>3, 8 slots/row) with row&7 -> fragment reads go 16-way -> 2-way.
__device__ __forceinline__ int p_idx(int row, int col) {
  return row * 64 + ((((col >> 3) ^ (row & 7)) << 3) | (col & 7));
}

// ---------- prep kernels ----------

__global__ __launch_bounds__(256) void cvt_bf16(const float* __restrict__ src,
                                                u16* __restrict__ dst, int n) {
  int i = (blockIdx.x * 256 + threadIdx.x) * 4;
  if (i + 3 < n) {
    float4 f = *(const float4*)(src + i);
    ushort4 o;
    o.x = f2bf(f.x); o.y = f2bf(f.y); o.z = f2bf(f.z); o.w = f2bf(f.w);
    *(ushort4*)(dst + i) = o;
  }
}

// bias[h][i][j] = table[rel_index[i*49+j]*16 + h]
__global__ __launch_bounds__(256) void build_bias(const float* __restrict__ tbl,
                                                  const int* __restrict__ ridx,
                                                  float* __restrict__ biasf) {
  int t = blockIdx.x * 256 + threadIdx.x;
  if (t < 16 * 2401) {
    int h = t / 2401, ij = t % 2401;
    biasf[t] = tbl[ridx[ij] * 16 + h];
  }
}

// ---------- GEMM: C[M][N] = A[M][K] * B[N][K]^T + bias[N] ----------
// A,B bf16 row-major (K contiguous). 128x128 tile, BK=32, 256 threads,
// 4 waves in 2x2, each wave 64x64 via 4x4 grid of 16x16x32 MFMAs.
// Swapped-operand accumulator: D[row=quad*4+r -> n][col=lo -> m] so each lane
// holds 4 consecutive N-columns -> vectorized bias load + 8B/16B stores.
// LDS tiles XOR-swizzled (k-slot ^ (row>>1)&3) against 8-way bank conflicts;
// swizzle realized as pre-swizzled *global source* since global_load_lds
// writes linearly (both-sides-or-neither rule).

template <bool OUT_BF16>
__global__ __launch_bounds__(256) void gemm_bt(const u16* __restrict__ A,
                                               const u16* __restrict__ B,
                                               const float* __restrict__ bias,
                                               void* __restrict__ C,
                                               int M, int N, int K) {
  __shared__ u16 As[128 * 32];
  __shared__ u16 Bs[128 * 32];
  const int t = threadIdx.x;
  const int w = t >> 6, l = t & 63;
  const int quad = l >> 4, lo = l & 15;

  // XCD-chunked bijective blockIdx swizzle (valid when nwg % 8 == 0):
  // each XCD gets a contiguous m-range -> A panels fetched by one XCD only.
  int bx = blockIdx.x, by = blockIdx.y;
  {
    const int nwg = gridDim.x * gridDim.y;
    if ((nwg & 7) == 0) {
      const int lin = bx + gridDim.x * by;
      const int swz = (lin & 7) * (nwg >> 3) + (lin >> 3);
      bx = swz % gridDim.x;
      by = swz / gridDim.x;
    }
  }
  const long m0 = (long)by * 128;
  const long n0 = (long)bx * 128;
  const int wm = (w >> 1) * 64, wn = (w & 1) * 64;

  f32x4 acc[4][4] = {};

  // staging: chunk id = (w*2+i)*64 + l ; row = chunk/4 ; k-slot = chunk%4
  // pre-swizzle: LDS slot s holds global k-octet s ^ ((row>>1)&3)
  const int srow0 = w * 32 + (l >> 2);
  const int skc = ((l & 3) ^ ((srow0 >> 1) & 3)) * 8;  // same XOR for row+16
  const u16* gA = A + (m0 + srow0) * (long)K + skc;
  const u16* gB = B + (n0 + srow0) * (long)K + skc;
  u16* lA = As + (w * 128 + l) * 8;
  u16* lB = Bs + (w * 128 + l) * 8;

  for (int k0 = 0; k0 < K; k0 += 32) {
    gl_lds16(gA + k0, lA);
    gl_lds16(gA + 16 * (long)K + k0, lA + 64 * 8);
    gl_lds16(gB + k0, lB);
    gl_lds16(gB + 16 * (long)K + k0, lB + 64 * 8);
    __syncthreads();

    s16x8 af[4], bfv[4];
#pragma unroll
    for (int i = 0; i < 4; ++i) {
      const int ra = wm + i * 16 + lo;
      const int rb = wn + i * 16 + lo;
      af[i]  = *(const s16x8*)(As + ra * 32 + ((quad ^ ((ra >> 1) & 3)) << 3));
      bfv[i] = *(const s16x8*)(Bs + rb * 32 + ((quad ^ ((rb >> 1) & 3)) << 3));
    }
#pragma unroll
    for (int mt = 0; mt < 4; ++mt)
#pragma unroll
      for (int nt = 0; nt < 4; ++nt)
        acc[mt][nt] = mfma_bf16_16x16x32(bfv[nt], af[mt], acc[mt][nt]);
    __syncthreads();
  }

  // epilogue: lane holds C[m = ..+lo][n = ..+quad*4 + (0..3)]
#pragma unroll
  for (int mt = 0; mt < 4; ++mt) {
    const long m = m0 + wm + mt * 16 + lo;
#pragma unroll
    for (int nt = 0; nt < 4; ++nt) {
      const long n = n0 + wn + nt * 16 + quad * 4;
      const float4 bv = *(const float4*)(bias + n);
      const float v0 = acc[mt][nt][0] + bv.x;
      const float v1 = acc[mt][nt][1] + bv.y;
      const float v2 = acc[mt][nt][2] + bv.z;
      const float v3 = acc[mt][nt][3] + bv.w;
      const long off = m * (long)N + n;
      if (OUT_BF16) {
        uint2 o;
        o.x = (unsigned)f2bf(v0) | ((unsigned)f2bf(v1) << 16);
        o.y = (unsigned)f2bf(v2) | ((unsigned)f2bf(v3) << 16);
        *(uint2*)((u16*)C + off) = o;
      } else {
        float4 o = make_float4(v0, v1, v2, v3);
        *(float4*)((float*)C + off) = o;
      }
    }
  }
}

// ---------- fused window attention ----------
// one wave per (window b, head h); 4 waves/block
// qkv row layout: col = s*512 + h*32 + d (s=0 q, 1 k, 2 v), row stride 1536

__global__ __launch_bounds__(256) void attn_kernel(const u16* __restrict__ qkv,
                                                   const float* __restrict__ biasf,
                                                   const float* __restrict__ mask,
                                                   u16* __restrict__ ao) {
  __shared__ u16 P[4][64 * 64];  // per-wave P tile, bf16, XOR-swizzled
  const int t = threadIdx.x;
  const int w = t >> 6, l = t & 63;
  const int quad = l >> 4, lo = l & 15;
  const int u = blockIdx.x * 4 + w;
  const int b = u >> 4, h = u & 15;

  const u16* qp = qkv + (long)b * 49 * 1536 + h * 32;
  const u16* kp = qp + 512;
  const u16* vp = qp + 1024;

  const s16x8 zero8 = {};
  s16x8 qf[4], kf[4];
#pragma unroll
  for (int mt = 0; mt < 4; ++mt) {
    int m = mt * 16 + lo;
    qf[mt] = (m < 49) ? *(const s16x8*)(qp + (long)m * 1536 + quad * 8) : zero8;
    kf[mt] = (m < 49) ? *(const s16x8*)(kp + (long)m * 1536 + quad * 8) : zero8;
  }

  f32x4 S[4][4] = {};
#pragma unroll
  for (int mt = 0; mt < 4; ++mt)
#pragma unroll
    for (int nt = 0; nt < 4; ++nt)
      S[mt][nt] = mfma_bf16_16x16x32(qf[mt], kf[nt], S[mt][nt]);

  const float scale = 0.17677669529663687f;  // 32^-0.5
  const float* bh = biasf + h * 2401;
  const float* mw = mask + (long)(b & 63) * 2401;

  // logits + row softmax. Row = mt*16 + quad*4 + r lives in one 16-lane group.
#pragma unroll
  for (int mt = 0; mt < 4; ++mt) {
#pragma unroll
    for (int r = 0; r < 4; ++r) {
      int row = mt * 16 + quad * 4 + r;
      int rr = row < 49 ? row : 48;  // clamp: rows >=49 are dead, keep reads in-bounds
      float vals[4];
#pragma unroll
      for (int nt = 0; nt < 4; ++nt) {
        int col = nt * 16 + lo;
        vals[nt] = (col < 49)
                       ? S[mt][nt][r] * scale + bh[rr * 49 + col] + mw[rr * 49 + col]
                       : -1e30f;
      }
      float rm = fmaxf(fmaxf(vals[0], vals[1]), fmaxf(vals[2], vals[3]));
#pragma unroll
      for (int off = 1; off < 16; off <<= 1) rm = fmaxf(rm, __shfl_xor(rm, off, 16));
      float s = 0.f;
#pragma unroll
      for (int nt = 0; nt < 4; ++nt) {
        vals[nt] = __expf(vals[nt] - rm);
        s += vals[nt];
      }
#pragma unroll
      for (int off = 1; off < 16; off <<= 1) s += __shfl_xor(s, off, 16);
      float is = 1.f / s;
#pragma unroll
      for (int nt = 0; nt < 4; ++nt) S[mt][nt][r] = vals[nt] * is;
    }
  }

  // P (C-layout) -> LDS 64x64 bf16 (swizzled), then reload as A-operand frags
  u16* pw = &P[w][0];
#pragma unroll
  for (int mt = 0; mt < 4; ++mt)
#pragma unroll
    for (int nt = 0; nt < 4; ++nt)
#pragma unroll
      for (int r = 0; r < 4; ++r)
        pw[p_idx(mt * 16 + quad * 4 + r, nt * 16 + lo)] = f2bf(S[mt][nt][r]);

  // O = P * V : M=64, N=32 (2 tiles), K=64 (2 tiles of 32)
  // Swapped operands: O^T frag, lane holds O[q=lo][d = ..+quad*4+(0..3)]
  f32x4 O[4][2] = {};
#pragma unroll
  for (int kt = 0; kt < 2; ++kt) {
    s16x8 vb[2];
#pragma unroll
    for (int nt = 0; nt < 2; ++nt) {
      union { u16 us[8]; s16x8 v; } tb;
#pragma unroll
      for (int jj = 0; jj < 8; ++jj) {
        int j = kt * 32 + quad * 8 + jj;
        tb.us[jj] = (j < 49) ? vp[(long)j * 1536 + nt * 16 + lo] : (u16)0;
      }
      vb[nt] = tb.v;
    }
#pragma unroll
    for (int mt = 0; mt < 4; ++mt) {
      s16x8 pa = *(const s16x8*)(pw + p_idx(mt * 16 + lo, kt * 32 + quad * 8));
      O[mt][0] = mfma_bf16_16x16x32(vb[0], pa, O[mt][0]);
      O[mt][1] = mfma_bf16_16x16x32(vb[1], pa, O[mt][1]);
    }
  }

  // store attn_out[b*49+q][h*32 + d], bf16: one 8B store per (mt,nt)
  u16* op = ao + (long)b * 49 * 512 + h * 32;
#pragma unroll
  for (int mt = 0; mt < 4; ++mt) {
    const int q = mt * 16 + lo;
    if (q < 49) {
#pragma unroll
      for (int nt = 0; nt < 2; ++nt) {
        const int d = nt * 16 + quad * 4;
        uint2 o;
        o.x = (unsigned)f2bf(O[mt][nt][0]) | ((unsigned)f2bf(O[mt][nt][1]) << 16);
        o.y = (unsigned)f2bf(O[mt][nt][2]) | ((unsigned)f2bf(O[mt][nt][3]) << 16);
        *(uint2*)(op + (long)q * 512 + d) = o;
      }
    }
  }
}

// ---------- launch ----------

extern "C" void kernel_launch(void* const* d_in, const int* in_sizes, int n_in,
                              void* d_out, int out_size, void* d_ws, size_t ws_size,
                              hipStream_t stream) {
  const float* x      = (const float*)d_in[0];
  const float* mask   = (const float*)d_in[1];
  const float* qkv_w  = (const float*)d_in[2];
  const float* qkv_b  = (const float*)d_in[3];
  const float* proj_w = (const float*)d_in[4];
  const float* proj_b = (const float*)d_in[5];
  const float* tbl    = (const float*)d_in[6];
  const int*   ridx   = (const int*)d_in[7];

  // ws layout (bf16 elements unless noted):
  // xb: 100352*512      = 51,380,224   (reused as attn_out after GEMM1)
  // qkvb: 100352*1536   = 154,140,672
  // wq: 1536*512        = 786,432
  // wp: 512*512         = 262,144
  // biasf: 16*49*49 fp32
  u16* xb    = (u16*)d_ws;
  u16* qkvb  = xb + 51380224;
  u16* wq    = qkvb + 154140672;
  u16* wp    = wq + 786432;
  float* biasf = (float*)(wp + 262144);

  cvt_bf16<<<50176, 256, 0, stream>>>(x, xb, 51380224);
  cvt_bf16<<<768, 256, 0, stream>>>(qkv_w, wq, 786432);
  cvt_bf16<<<256, 256, 0, stream>>>(proj_w, wp, 262144);
  build_bias<<<151, 256, 0, stream>>>(tbl, ridx, biasf);

  // qkv = x @ qkv_w^T + qkv_b   (bf16 out)
  gemm_bt<true><<<dim3(12, 784), 256, 0, stream>>>(xb, wq, qkv_b, qkvb,
                                                   100352, 1536, 512);
  // attention -> attn_out (reuse xb region)
  attn_kernel<<<8192, 256, 0, stream>>>(qkvb, biasf, mask, xb);

  // out = attn_out @ proj_w^T + proj_b   (fp32 out)
  gemm_bt<false><<<dim3(4, 784), 256, 0, stream>>>(xb, wp, proj_b, d_out,
                                                   100352, 512, 512);
}

// Round 2
// 899.511 us; speedup vs baseline: 1.1460x; 1.1460x over previous
//
#include <hip/hip_runtime.h>

typedef unsigned short u16;
typedef short s16x8 __attribute__((ext_vector_type(8)));
typedef __bf16 bf16x8 __attribute__((ext_vector_type(8)));
typedef float f32x4 __attribute__((ext_vector_type(4)));

// ---------- helpers ----------

__device__ __forceinline__ u16 f2bf(float f) {
  union { float f; unsigned u; } x; x.f = f;
  unsigned r = (x.u + 0x7fffu + ((x.u >> 16) & 1u)) >> 16;  // RNE
  return (u16)r;
}

__device__ __forceinline__ f32x4 mfma_bf16_16x16x32(s16x8 a, s16x8 b, f32x4 c) {
  return __builtin_amdgcn_mfma_f32_16x16x32_bf16(
      __builtin_bit_cast(bf16x8, a), __builtin_bit_cast(bf16x8, b), c, 0, 0, 0);
}

__device__ __forceinline__ void gl_lds16(const u16* g, u16* l) {
  __builtin_amdgcn_global_load_lds(
      (__attribute__((address_space(1))) unsigned int*)g,
      (__attribute__((address_space(3))) unsigned int*)l, 16, 0, 0);
}

// P-tile LDS swizzle: [64][64] u16 (128B row stride). XOR the 16B-slot index
// (col>>3, 8 slots/row) with row&7 -> A-frag read goes 16-way -> 2-way (free).
__device__ __forceinline__ int p_idx(int row, int col) {
  return row * 64 + ((((col >> 3) ^ (row & 7)) << 3) | (col & 7));
}

// ---------- prep kernels ----------

__global__ __launch_bounds__(256) void cvt_bf16(const float* __restrict__ src,
                                                u16* __restrict__ dst, int n) {
  int i = (blockIdx.x * 256 + threadIdx.x) * 4;
  if (i + 3 < n) {
    float4 f = *(const float4*)(src + i);
    ushort4 o;
    o.x = f2bf(f.x); o.y = f2bf(f.y); o.z = f2bf(f.z); o.w = f2bf(f.w);
    *(ushort4*)(dst + i) = o;
  }
}

// bias[h][i][j] = table[rel_index[i*49+j]*16 + h]
__global__ __launch_bounds__(256) void build_bias(const float* __restrict__ tbl,
                                                  const int* __restrict__ ridx,
                                                  float* __restrict__ biasf) {
  int t = blockIdx.x * 256 + threadIdx.x;
  if (t < 16 * 2401) {
    int h = t / 2401, ij = t % 2401;
    biasf[t] = tbl[ridx[ij] * 16 + h];
  }
}

// ---------- GEMM: C[M][N] = A[M][K] * B[N][K]^T + bias[N] ----------
// A,B bf16 row-major (K contiguous). 128x128 tile, BK=32, 256 threads,
// 4 waves in 2x2, each wave 64x64 via 4x4 grid of 16x16x32 MFMAs.
// T3 minimum 2-phase: double-buffered LDS, STAGE(next) issued BEFORE
// compute(cur), ONE barrier per K-step (its vmcnt(0) drain lands after the
// MFMAs, so load latency hides under compute).
// LDS k-slot XOR-swizzled vs 8-way conflicts (pre-swizzled GLOBAL source,
// linear LDS dest — both-sides-or-neither rule for global_load_lds).
// XCD-chunked blockIdx swizzle: contiguous m-range per XCD (FETCH -83%, R1).

template <bool OUT_BF16>
__global__ __launch_bounds__(256) void gemm_bt(const u16* __restrict__ A,
                                               const u16* __restrict__ B,
                                               const float* __restrict__ bias,
                                               void* __restrict__ C,
                                               int M, int N, int K) {
  __shared__ u16 As[2][128 * 32];
  __shared__ u16 Bs[2][128 * 32];
  const int t = threadIdx.x;
  const int w = t >> 6, l = t & 63;
  const int quad = l >> 4, lo = l & 15;

  int bx = blockIdx.x, by = blockIdx.y;
  {
    const int nwg = gridDim.x * gridDim.y;
    if ((nwg & 7) == 0) {
      const int lin = bx + gridDim.x * by;
      const int swz = (lin & 7) * (nwg >> 3) + (lin >> 3);
      bx = swz % gridDim.x;
      by = swz / gridDim.x;
    }
  }
  const long m0 = (long)by * 128;
  const long n0 = (long)bx * 128;
  const int wm = (w >> 1) * 64, wn = (w & 1) * 64;

  f32x4 acc[4][4] = {};

  // staging: chunk id = (w*2+i)*64 + l ; row = chunk/4 ; k-slot = chunk%4
  // pre-swizzle: LDS slot s holds global k-octet s ^ ((row>>1)&3)
  const int srow0 = w * 32 + (l >> 2);
  const int skc = ((l & 3) ^ ((srow0 >> 1) & 3)) * 8;  // same XOR for row+16
  const u16* gA = A + (m0 + srow0) * (long)K + skc;
  const u16* gB = B + (n0 + srow0) * (long)K + skc;
  const int lofs = (w * 128 + l) * 8;  // lane-linear 16B dest (gl_lds rule)

  const int NT = K >> 5;  // 16 K-steps

  // prologue: stage tile 0 into buffer 0
  gl_lds16(gA, As[0] + lofs);
  gl_lds16(gA + 16 * (long)K, As[0] + lofs + 64 * 8);
  gl_lds16(gB, Bs[0] + lofs);
  gl_lds16(gB + 16 * (long)K, Bs[0] + lofs + 64 * 8);
  __syncthreads();

  int cur = 0;
  for (int t0 = 0; t0 < NT; ++t0) {
    // issue next tile's loads into the other buffer (overlaps with MFMAs)
    if (t0 + 1 < NT) {
      const int k0 = (t0 + 1) << 5;
      gl_lds16(gA + k0, As[cur ^ 1] + lofs);
      gl_lds16(gA + 16 * (long)K + k0, As[cur ^ 1] + lofs + 64 * 8);
      gl_lds16(gB + k0, Bs[cur ^ 1] + lofs);
      gl_lds16(gB + 16 * (long)K + k0, Bs[cur ^ 1] + lofs + 64 * 8);
    }

    const u16* as = As[cur];
    const u16* bs = Bs[cur];
    s16x8 af[4], bfv[4];
#pragma unroll
    for (int i = 0; i < 4; ++i) {
      const int ra = wm + i * 16 + lo;
      const int rb = wn + i * 16 + lo;
      af[i]  = *(const s16x8*)(as + ra * 32 + ((quad ^ ((ra >> 1) & 3)) << 3));
      bfv[i] = *(const s16x8*)(bs + rb * 32 + ((quad ^ ((rb >> 1) & 3)) << 3));
    }
#pragma unroll
    for (int mt = 0; mt < 4; ++mt)
#pragma unroll
      for (int nt = 0; nt < 4; ++nt)
        acc[mt][nt] = mfma_bf16_16x16x32(af[mt], bfv[nt], acc[mt][nt]);

    // single barrier per K-step: drains the prefetch (vmcnt) AND fences
    // buffer reuse (everyone done reading buf[cur] before next overwrite)
    __syncthreads();
    cur ^= 1;
  }

  // epilogue: D[row = quad*4+r][col = lane&15] — 2B stores, 16 lanes give
  // 32B contiguous segments (coalesced)
#pragma unroll
  for (int mt = 0; mt < 4; ++mt) {
#pragma unroll
    for (int nt = 0; nt < 4; ++nt) {
      long col = n0 + wn + nt * 16 + lo;
      float bv = bias[col];
      long rowb = m0 + wm + mt * 16 + quad * 4;
#pragma unroll
      for (int r = 0; r < 4; ++r) {
        float v = acc[mt][nt][r] + bv;
        long off = (rowb + r) * (long)N + col;
        if (OUT_BF16) ((u16*)C)[off] = f2bf(v);
        else          ((float*)C)[off] = v;
      }
    }
  }
}

// ---------- fused window attention ----------
// one wave per (window b, head h); 4 waves/block
// qkv row layout: col = s*512 + h*32 + d (s=0 q, 1 k, 2 v), row stride 1536

__global__ __launch_bounds__(256) void attn_kernel(const u16* __restrict__ qkv,
                                                   const float* __restrict__ biasf,
                                                   const float* __restrict__ mask,
                                                   u16* __restrict__ ao) {
  __shared__ u16 P[4][64 * 64];  // per-wave P tile, bf16, XOR-swizzled
  const int t = threadIdx.x;
  const int w = t >> 6, l = t & 63;
  const int quad = l >> 4, lo = l & 15;
  const int u = blockIdx.x * 4 + w;
  const int b = u >> 4, h = u & 15;

  const u16* qp = qkv + (long)b * 49 * 1536 + h * 32;
  const u16* kp = qp + 512;
  const u16* vp = qp + 1024;

  const s16x8 zero8 = {};
  s16x8 qf[4], kf[4];
#pragma unroll
  for (int mt = 0; mt < 4; ++mt) {
    int m = mt * 16 + lo;
    qf[mt] = (m < 49) ? *(const s16x8*)(qp + (long)m * 1536 + quad * 8) : zero8;
    kf[mt] = (m < 49) ? *(const s16x8*)(kp + (long)m * 1536 + quad * 8) : zero8;
  }

  f32x4 S[4][4] = {};
#pragma unroll
  for (int mt = 0; mt < 4; ++mt)
#pragma unroll
    for (int nt = 0; nt < 4; ++nt)
      S[mt][nt] = mfma_bf16_16x16x32(qf[mt], kf[nt], S[mt][nt]);

  const float scale = 0.17677669529663687f;  // 32^-0.5
  const float* bh = biasf + h * 2401;
  const float* mw = mask + (long)(b & 63) * 2401;

  // logits + row softmax. Row = mt*16 + quad*4 + r lives in one 16-lane group.
#pragma unroll
  for (int mt = 0; mt < 4; ++mt) {
#pragma unroll
    for (int r = 0; r < 4; ++r) {
      int row = mt * 16 + quad * 4 + r;
      int rr = row < 49 ? row : 48;  // clamp: rows >=49 are dead, keep reads in-bounds
      float vals[4];
#pragma unroll
      for (int nt = 0; nt < 4; ++nt) {
        int col = nt * 16 + lo;
        vals[nt] = (col < 49)
                       ? S[mt][nt][r] * scale + bh[rr * 49 + col] + mw[rr * 49 + col]
                       : -1e30f;
      }
      float rm = fmaxf(fmaxf(vals[0], vals[1]), fmaxf(vals[2], vals[3]));
#pragma unroll
      for (int off = 1; off < 16; off <<= 1) rm = fmaxf(rm, __shfl_xor(rm, off, 16));
      float s = 0.f;
#pragma unroll
      for (int nt = 0; nt < 4; ++nt) {
        vals[nt] = __expf(vals[nt] - rm);
        s += vals[nt];
      }
#pragma unroll
      for (int off = 1; off < 16; off <<= 1) s += __shfl_xor(s, off, 16);
      float is = 1.f / s;
#pragma unroll
      for (int nt = 0; nt < 4; ++nt) S[mt][nt][r] = vals[nt] * is;
    }
  }

  // P (C-layout) -> LDS 64x64 bf16 (XOR-swizzled), reload as A-operand frags
  u16* pw = &P[w][0];
#pragma unroll
  for (int mt = 0; mt < 4; ++mt)
#pragma unroll
    for (int nt = 0; nt < 4; ++nt)
#pragma unroll
      for (int r = 0; r < 4; ++r)
        pw[p_idx(mt * 16 + quad * 4 + r, nt * 16 + lo)] = f2bf(S[mt][nt][r]);

  // O = P * V : M=64, N=32 (2 tiles), K=64 (2 tiles of 32)
  f32x4 O[4][2] = {};
#pragma unroll
  for (int kt = 0; kt < 2; ++kt) {
    s16x8 vb[2];
#pragma unroll
    for (int nt = 0; nt < 2; ++nt) {
      union { u16 us[8]; s16x8 v; } tb;
#pragma unroll
      for (int jj = 0; jj < 8; ++jj) {
        int j = kt * 32 + quad * 8 + jj;
        tb.us[jj] = (j < 49) ? vp[(long)j * 1536 + nt * 16 + lo] : (u16)0;
      }
      vb[nt] = tb.v;
    }
#pragma unroll
    for (int mt = 0; mt < 4; ++mt) {
      s16x8 pa = *(const s16x8*)(pw + p_idx(mt * 16 + lo, kt * 32 + quad * 8));
      O[mt][0] = mfma_bf16_16x16x32(pa, vb[0], O[mt][0]);
      O[mt][1] = mfma_bf16_16x16x32(pa, vb[1], O[mt][1]);
    }
  }

  // store attn_out[b*49+row][h*32 + d], bf16 — 2B stores, 16-lane col groups
  // coalesce into 32B segments
  u16* op = ao + (long)b * 49 * 512 + h * 32;
#pragma unroll
  for (int mt = 0; mt < 4; ++mt)
#pragma unroll
    for (int nt = 0; nt < 2; ++nt)
#pragma unroll
      for (int r = 0; r < 4; ++r) {
        int row = mt * 16 + quad * 4 + r;
        if (row < 49) op[(long)row * 512 + nt * 16 + lo] = f2bf(O[mt][nt][r]);
      }
}

// ---------- launch ----------

extern "C" void kernel_launch(void* const* d_in, const int* in_sizes, int n_in,
                              void* d_out, int out_size, void* d_ws, size_t ws_size,
                              hipStream_t stream) {
  const float* x      = (const float*)d_in[0];
  const float* mask   = (const float*)d_in[1];
  const float* qkv_w  = (const float*)d_in[2];
  const float* qkv_b  = (const float*)d_in[3];
  const float* proj_w = (const float*)d_in[4];
  const float* proj_b = (const float*)d_in[5];
  const float* tbl    = (const float*)d_in[6];
  const int*   ridx   = (const int*)d_in[7];

  // ws layout (bf16 elements unless noted):
  // xb: 100352*512      = 51,380,224   (reused as attn_out after GEMM1)
  // qkvb: 100352*1536   = 154,140,672
  // wq: 1536*512        = 786,432
  // wp: 512*512         = 262,144
  // biasf: 16*49*49 fp32
  u16* xb    = (u16*)d_ws;
  u16* qkvb  = xb + 51380224;
  u16* wq    = qkvb + 154140672;
  u16* wp    = wq + 786432;
  float* biasf = (float*)(wp + 262144);

  cvt_bf16<<<50176, 256, 0, stream>>>(x, xb, 51380224);
  cvt_bf16<<<768, 256, 0, stream>>>(qkv_w, wq, 786432);
  cvt_bf16<<<256, 256, 0, stream>>>(proj_w, wp, 262144);
  build_bias<<<151, 256, 0, stream>>>(tbl, ridx, biasf);

  // qkv = x @ qkv_w^T + qkv_b   (bf16 out)
  gemm_bt<true><<<dim3(12, 784), 256, 0, stream>>>(xb, wq, qkv_b, qkvb,
                                                   100352, 1536, 512);
  // attention -> attn_out (reuse xb region)
  attn_kernel<<<8192, 256, 0, stream>>>(qkvb, biasf, mask, xb);

  // out = attn_out @ proj_w^T + proj_b   (fp32 out)
  gemm_bt<false><<<dim3(4, 784), 256, 0, stream>>>(xb, wp, proj_b, d_out,
                                                   100352, 512, 512);
}